// Round 2
// baseline (1016.193 us; speedup 1.0000x reference)
//
#include <hip/hip_runtime.h>
#include <hip/hip_bf16.h>

// ---------------- types & helpers ----------------
typedef __attribute__((ext_vector_type(4))) float  f32x4;
typedef __attribute__((ext_vector_type(8))) __bf16 bf16x8;

typedef __attribute__((address_space(1))) void gvoid_t;
typedef __attribute__((address_space(3))) void lvoid_t;

__device__ __forceinline__ void gld16(const void* g, void* l) {
    // async global->LDS, 16B per lane; LDS dest = wave-uniform base + lane*16
    __builtin_amdgcn_global_load_lds((const gvoid_t*)g, (lvoid_t*)l, 16, 0, 0);
}

__device__ __forceinline__ unsigned short f2bf(float f) {
    unsigned u = __builtin_bit_cast(unsigned, f);
    u += 0x7fffu + ((u >> 16) & 1u);
    return (unsigned short)(u >> 16);
}

__device__ __forceinline__ float silu(float x) {
    return x / (1.f + __expf(-x));
}

// ---------------- weight transpose + fp32->bf16 ----------------
// in: K x N fp32 (row-major). out: Npad x K bf16 (row-major), rows n>=N are zero.
__global__ __launch_bounds__(256) void k_transpose_cvt(const float* __restrict__ in,
                                                       unsigned short* __restrict__ out,
                                                       int K, int N, int Npad) {
    __shared__ float t[32][33];
    int bn = blockIdx.x * 32;   // over N (output rows)
    int bk = blockIdx.y * 32;   // over K
    int c = threadIdx.x & 31, r0 = threadIdx.x >> 5;   // 8 rows per pass
    #pragma unroll
    for (int rr = r0; rr < 32; rr += 8) {
        int k = bk + rr, n = bn + c;
        t[rr][c] = (k < K && n < N) ? in[(size_t)k * N + n] : 0.f;
    }
    __syncthreads();
    #pragma unroll
    for (int rr = r0; rr < 32; rr += 8) {
        int n = bn + rr, k = bk + c;
        if (n < Npad && k < K) out[(size_t)n * K + k] = f2bf(t[c][rr]);
    }
}

// ---------------- LayerNorm -> bf16 ----------------
__global__ __launch_bounds__(256) void k_ln(const float* __restrict__ x,
                                            const float* __restrict__ g,
                                            const float* __restrict__ b,
                                            unsigned short* __restrict__ xn) {
    int row = blockIdx.x;                       // 0..2047 (b*L+l)
    const float4* xr = (const float4*)(x + (size_t)row * 1024);
    float4 v = xr[threadIdx.x];
    float s  = v.x + v.y + v.z + v.w;
    float ss = v.x*v.x + v.y*v.y + v.z*v.z + v.w*v.w;
    #pragma unroll
    for (int o = 32; o > 0; o >>= 1) { s += __shfl_down(s, o); ss += __shfl_down(ss, o); }
    __shared__ float red[8];
    if ((threadIdx.x & 63) == 0) { red[threadIdx.x >> 6] = s; red[4 + (threadIdx.x >> 6)] = ss; }
    __syncthreads();
    s  = red[0] + red[1] + red[2] + red[3];
    ss = red[4] + red[5] + red[6] + red[7];
    float mu  = s * (1.f / 1024.f);
    float inv = rsqrtf(ss * (1.f / 1024.f) - mu * mu + 1e-5f);
    float4 gv = ((const float4*)g)[threadIdx.x];
    float4 bv = ((const float4*)b)[threadIdx.x];
    ushort4 o4;
    o4.x = f2bf((v.x - mu) * inv * gv.x + bv.x);
    o4.y = f2bf((v.y - mu) * inv * gv.y + bv.y);
    o4.z = f2bf((v.z - mu) * inv * gv.z + bv.z);
    o4.w = f2bf((v.w - mu) * inv * gv.w + bv.w);
    ((ushort4*)xn)[(size_t)row * 256 + threadIdx.x] = o4;
}

// ---------------- generic bf16 MFMA GEMM ----------------
// C(MxN fp32,ldc) = A(MxK bf16 row-major,lda) @ Bt(NxK bf16 row-major,ldb)^T
// block tile 128x128, BK=32, 4 waves (2x2), each wave 64x64 = 4x4 frags of 16x16.
// M,N multiples of 128; K multiple of 32. EPI: 0=none, 1=softplus(x+bias[col])
template <int EPI>
__global__ __launch_bounds__(256) void k_gemm(const unsigned short* __restrict__ A,
                                              const unsigned short* __restrict__ Bt,
                                              float* __restrict__ C,
                                              int K, int lda, int ldb, int ldc,
                                              const float* __restrict__ bias) {
    __shared__ __attribute__((aligned(16))) unsigned short smA[128 * 32];
    __shared__ __attribute__((aligned(16))) unsigned short smB[128 * 32];

    int tid  = threadIdx.x;
    int wave = tid >> 6, lane = tid & 63;
    int bm = blockIdx.x * 128, bn = blockIdx.y * 128;
    int wm = (wave >> 1) * 64, wn = (wave & 1) * 64;
    int lr = lane & 15, lk = (lane >> 4) * 8;

    int srow = tid >> 2;            // 0..63  (+ p*64)
    int scol = (tid & 3) << 3;      // 0,8,16,24

    f32x4 acc[4][4] = {};

    for (int k0 = 0; k0 < K; k0 += 32) {
        #pragma unroll
        for (int p = 0; p < 2; ++p) {
            const unsigned short* ga = A  + (size_t)(bm + p * 64 + srow) * lda + k0 + scol;
            const unsigned short* gb = Bt + (size_t)(bn + p * 64 + srow) * ldb + k0 + scol;
            gld16(ga, smA + p * 2048 + wave * 512);
            gld16(gb, smB + p * 2048 + wave * 512);
        }
        __syncthreads();
        bf16x8 af[4], bf[4];
        #pragma unroll
        for (int i = 0; i < 4; ++i) {
            af[i] = *(const bf16x8*)(smA + (wm + i * 16 + lr) * 32 + lk);
            bf[i] = *(const bf16x8*)(smB + (wn + i * 16 + lr) * 32 + lk);
        }
        #pragma unroll
        for (int mi = 0; mi < 4; ++mi)
            #pragma unroll
            for (int ni = 0; ni < 4; ++ni)
                acc[mi][ni] = __builtin_amdgcn_mfma_f32_16x16x32_bf16(af[mi], bf[ni], acc[mi][ni], 0, 0, 0);
        __syncthreads();
    }

    #pragma unroll
    for (int mi = 0; mi < 4; ++mi) {
        #pragma unroll
        for (int ni = 0; ni < 4; ++ni) {
            int c = bn + wn + ni * 16 + lr;
            #pragma unroll
            for (int v = 0; v < 4; ++v) {
                int r = bm + wm + mi * 16 + ((lane >> 4) << 2) + v;
                float val = acc[mi][ni][v];
                if (EPI == 1) {
                    val += bias[c];
                    val = (val > 20.f) ? val : log1pf(__expf(val));
                }
                C[(size_t)r * ldc + c] = val;
            }
        }
    }
}

// ---------------- causal depthwise conv (width 4) + SiLU ----------------
__global__ __launch_bounds__(256) void k_conv(const float* __restrict__ uz,
                                              const float* __restrict__ cw,
                                              const float* __restrict__ cb,
                                              float* __restrict__ uc,
                                              unsigned short* __restrict__ ucb) {
    int idx = blockIdx.x * 256 + threadIdx.x;   // over (b*L+l)*2048 + e
    int e  = idx & 2047;
    int bl = idx >> 11;
    int l  = bl & 1023;
    float acc = cb[e];
    const float* w = cw + e * 4;
    #pragma unroll
    for (int k = 0; k < 4; ++k) {
        int ls = l - 3 + k;
        if (ls >= 0) acc += w[k] * uz[(size_t)(bl - 3 + k) * 4096 + e];
    }
    float s = silu(acc);
    uc[idx]  = s;
    ucb[idx] = f2bf(s);
}

// ---------------- dbl[:, :64] -> bf16 ----------------
__global__ __launch_bounds__(256) void k_cvt_dtr(const float* __restrict__ dbl,
                                                 unsigned short* __restrict__ dtr) {
    int idx = blockIdx.x * 256 + threadIdx.x;   // 2048*64
    int r = idx >> 6, c = idx & 63;
    dtr[idx] = f2bf(dbl[(size_t)r * 128 + c]);
}

// ---------------- selective-scan + skip + gate ----------------
// 16 lanes per (b,e) sequence: lane n owns state n. Serial over L.
__global__ __launch_bounds__(256) void k_scan(const float* __restrict__ dt,
                                              const float* __restrict__ uc,
                                              const float* __restrict__ dbl,
                                              const float* __restrict__ uz,
                                              const float* __restrict__ A_log,
                                              const float* __restrict__ D_skip,
                                              unsigned short* __restrict__ yg) {
    int b  = blockIdx.x >> 7;                    // 2 b's * 128 blocks
    int e0 = (blockIdx.x & 127) * 16;
    int g = threadIdx.x >> 4, n = threadIdx.x & 15;
    int e = e0 + g;
    float Aen = -__expf(A_log[e * 16 + n]);
    float De  = D_skip[e];
    float h = 0.f;
    size_t base2 = (size_t)b * 1024 * 2048 + e;          // dt/uc/yg
    size_t base4 = (size_t)b * 1024 * 4096 + 2048 + e;   // z inside uz
    size_t based = (size_t)b * 1024 * 128;               // dbl rows
    #pragma unroll 4
    for (int l = 0; l < 1024; ++l) {
        float dtv = dt[base2];
        float ucv = uc[base2];
        float Bn  = dbl[based + 64 + n];
        float Cn  = dbl[based + 80 + n];
        float dA  = __expf(dtv * Aen);
        h = fmaf(dA, h, dtv * ucv * Bn);
        float p = h * Cn;
        p += __shfl_xor(p, 8, 16);
        p += __shfl_xor(p, 4, 16);
        p += __shfl_xor(p, 2, 16);
        p += __shfl_xor(p, 1, 16);
        if (n == 0) {
            float zv = uz[base4];
            float yv = (p + ucv * De) * silu(zv);
            yg[base2] = f2bf(yv);
        }
        base2 += 2048; base4 += 4096; based += 128;
    }
}

// ---------------- launch ----------------
extern "C" void kernel_launch(void* const* d_in, const int* in_sizes, int n_in,
                              void* d_out, int out_size, void* d_ws, size_t ws_size,
                              hipStream_t stream) {
    const float* x      = (const float*)d_in[0];
    const float* ln_g   = (const float*)d_in[1];
    const float* ln_b   = (const float*)d_in[2];
    const float* W_in   = (const float*)d_in[3];
    const float* conv_w = (const float*)d_in[4];
    const float* conv_b = (const float*)d_in[5];
    const float* W_x    = (const float*)d_in[6];
    const float* W_dt   = (const float*)d_in[7];
    const float* b_dt   = (const float*)d_in[8];
    const float* A_log  = (const float*)d_in[9];
    const float* D_skip = (const float*)d_in[10];
    const float* W_out  = (const float*)d_in[11];
    float* out = (float*)d_out;

    // ---- workspace guard: if ws is too small, skip cleanly (diagnostic:
    // a clean absmax failure next round means ws_size < needed, not a crash)
    const size_t needed =
        (size_t)4096 * 1024 * 2 + (size_t)1024 * 2048 * 2 + (size_t)2048 * 64 * 2 +
        (size_t)128 * 2048 * 2 + (size_t)2048 * 1024 * 2 + (size_t)2048 * 4096 * 4 +
        (size_t)2048 * 2048 * 4 + (size_t)2048 * 2048 * 2 + (size_t)2048 * 128 * 4 +
        (size_t)2048 * 64 * 2 + (size_t)2048 * 2048 * 4 + (size_t)2048 * 2048 * 2;
    if (ws_size < needed) return;

    char* w = (char*)d_ws;
    unsigned short* WIN_T  = (unsigned short*)w; w += (size_t)4096 * 1024 * 2;
    unsigned short* WOUT_T = (unsigned short*)w; w += (size_t)1024 * 2048 * 2;
    unsigned short* WDT_T  = (unsigned short*)w; w += (size_t)2048 * 64 * 2;
    unsigned short* WX_T   = (unsigned short*)w; w += (size_t)128 * 2048 * 2;
    unsigned short* XN     = (unsigned short*)w; w += (size_t)2048 * 1024 * 2;
    float*          UZ     = (float*)w;          w += (size_t)2048 * 4096 * 4;
    float*          UC     = (float*)w;          w += (size_t)2048 * 2048 * 4;
    unsigned short* UCB    = (unsigned short*)w; w += (size_t)2048 * 2048 * 2;
    float*          DBL    = (float*)w;          w += (size_t)2048 * 128 * 4;
    unsigned short* DTR    = (unsigned short*)w; w += (size_t)2048 * 64 * 2;
    float*          DT     = (float*)w;          w += (size_t)2048 * 2048 * 4;
    unsigned short* YG     = (unsigned short*)w; w += (size_t)2048 * 2048 * 2;

    // weight prep (transpose + bf16)
    k_transpose_cvt<<<dim3(128, 32), 256, 0, stream>>>(W_in,  WIN_T,  1024, 4096, 4096);
    k_transpose_cvt<<<dim3(32, 64),  256, 0, stream>>>(W_out, WOUT_T, 2048, 1024, 1024);
    k_transpose_cvt<<<dim3(64, 2),   256, 0, stream>>>(W_dt,  WDT_T,  64,   2048, 2048);
    k_transpose_cvt<<<dim3(4, 64),   256, 0, stream>>>(W_x,   WX_T,   2048, 96,   128);

    k_ln<<<2048, 256, 0, stream>>>(x, ln_g, ln_b, XN);

    // u,z = xn @ W_in   (2048x4096, K=1024)
    k_gemm<0><<<dim3(16, 32), 256, 0, stream>>>(XN, WIN_T, UZ, 1024, 1024, 1024, 4096, nullptr);

    k_conv<<<16384, 256, 0, stream>>>(UZ, conv_w, conv_b, UC, UCB);

    // dbl = uc @ W_x(padded)   (2048x128, K=2048)
    k_gemm<0><<<dim3(16, 1), 256, 0, stream>>>(UCB, WX_T, DBL, 2048, 2048, 2048, 128, nullptr);

    k_cvt_dtr<<<512, 256, 0, stream>>>(DBL, DTR);

    // dt = softplus(dtr @ W_dt + b_dt)   (2048x2048, K=64)
    k_gemm<1><<<dim3(16, 16), 256, 0, stream>>>(DTR, WDT_T, DT, 64, 64, 64, 2048, b_dt);

    k_scan<<<256, 256, 0, stream>>>(DT, UC, DBL, UZ, A_log, D_skip, YG);

    // out = yg @ W_out   (2048x1024, K=2048)
    k_gemm<0><<<dim3(16, 8), 256, 0, stream>>>(YG, WOUT_T, out, 2048, 2048, 2048, 1024, nullptr);
}

// Round 3
// 410.551 us; speedup vs baseline: 2.4752x; 2.4752x over previous
//
#include <hip/hip_runtime.h>
#include <hip/hip_bf16.h>

// ---------------- types & helpers ----------------
typedef __attribute__((ext_vector_type(4))) float  f32x4;
typedef __attribute__((ext_vector_type(8))) __bf16 bf16x8;

typedef __attribute__((address_space(1))) void gvoid_t;
typedef __attribute__((address_space(3))) void lvoid_t;

__device__ __forceinline__ void gld16(const void* g, void* l) {
    // async global->LDS, 16B per lane; LDS dest = wave-uniform base + lane*16
    __builtin_amdgcn_global_load_lds((const gvoid_t*)g, (lvoid_t*)l, 16, 0, 0);
}

__device__ __forceinline__ unsigned short f2bf(float f) {
    unsigned u = __builtin_bit_cast(unsigned, f);
    u += 0x7fffu + ((u >> 16) & 1u);
    return (unsigned short)(u >> 16);
}

__device__ __forceinline__ float silu(float x) {
    return x / (1.f + __expf(-x));
}

// ---------------- weight transpose + fp32->bf16 ----------------
// in: K x N fp32 (row-major). out: Npad x K bf16 (row-major), rows n>=N are zero.
__global__ __launch_bounds__(256) void k_transpose_cvt(const float* __restrict__ in,
                                                       unsigned short* __restrict__ out,
                                                       int K, int N, int Npad) {
    __shared__ float t[32][33];
    int bn = blockIdx.x * 32;   // over N (output rows)
    int bk = blockIdx.y * 32;   // over K
    int c = threadIdx.x & 31, r0 = threadIdx.x >> 5;   // 8 rows per pass
    #pragma unroll
    for (int rr = r0; rr < 32; rr += 8) {
        int k = bk + rr, n = bn + c;
        t[rr][c] = (k < K && n < N) ? in[(size_t)k * N + n] : 0.f;
    }
    __syncthreads();
    #pragma unroll
    for (int rr = r0; rr < 32; rr += 8) {
        int n = bn + rr, k = bk + c;
        if (n < Npad && k < K) out[(size_t)n * K + k] = f2bf(t[c][rr]);
    }
}

// ---------------- LayerNorm -> bf16 ----------------
__global__ __launch_bounds__(256) void k_ln(const float* __restrict__ x,
                                            const float* __restrict__ g,
                                            const float* __restrict__ b,
                                            unsigned short* __restrict__ xn) {
    int row = blockIdx.x;                       // 0..2047 (b*L+l)
    const float4* xr = (const float4*)(x + (size_t)row * 1024);
    float4 v = xr[threadIdx.x];
    float s  = v.x + v.y + v.z + v.w;
    float ss = v.x*v.x + v.y*v.y + v.z*v.z + v.w*v.w;
    #pragma unroll
    for (int o = 32; o > 0; o >>= 1) { s += __shfl_down(s, o); ss += __shfl_down(ss, o); }
    __shared__ float red[8];
    if ((threadIdx.x & 63) == 0) { red[threadIdx.x >> 6] = s; red[4 + (threadIdx.x >> 6)] = ss; }
    __syncthreads();
    s  = red[0] + red[1] + red[2] + red[3];
    ss = red[4] + red[5] + red[6] + red[7];
    float mu  = s * (1.f / 1024.f);
    float inv = rsqrtf(ss * (1.f / 1024.f) - mu * mu + 1e-5f);
    float4 gv = ((const float4*)g)[threadIdx.x];
    float4 bv = ((const float4*)b)[threadIdx.x];
    ushort4 o4;
    o4.x = f2bf((v.x - mu) * inv * gv.x + bv.x);
    o4.y = f2bf((v.y - mu) * inv * gv.y + bv.y);
    o4.z = f2bf((v.z - mu) * inv * gv.z + bv.z);
    o4.w = f2bf((v.w - mu) * inv * gv.w + bv.w);
    ((ushort4*)xn)[(size_t)row * 256 + threadIdx.x] = o4;
}

// ---------------- generic bf16 MFMA GEMM ----------------
// C(MxN fp32,ldc) = A(MxK bf16 row-major,lda) @ Bt(NxK bf16 row-major,ldb)^T
// block tile 128x128, BK=32, 4 waves (2x2), each wave 64x64 = 4x4 frags of 16x16.
// M,N multiples of 128; K multiple of 32. EPI: 0=none, 1=softplus(x+bias[col])
template <int EPI>
__global__ __launch_bounds__(256) void k_gemm(const unsigned short* __restrict__ A,
                                              const unsigned short* __restrict__ Bt,
                                              float* __restrict__ C,
                                              int K, int lda, int ldb, int ldc,
                                              const float* __restrict__ bias) {
    __shared__ __attribute__((aligned(16))) unsigned short smA[128 * 32];
    __shared__ __attribute__((aligned(16))) unsigned short smB[128 * 32];

    int tid  = threadIdx.x;
    int wave = tid >> 6, lane = tid & 63;
    int bm = blockIdx.x * 128, bn = blockIdx.y * 128;
    int wm = (wave >> 1) * 64, wn = (wave & 1) * 64;
    int lr = lane & 15, lk = (lane >> 4) * 8;

    int srow = tid >> 2;            // 0..63  (+ p*64)
    int scol = (tid & 3) << 3;      // 0,8,16,24

    f32x4 acc[4][4] = {};

    for (int k0 = 0; k0 < K; k0 += 32) {
        #pragma unroll
        for (int p = 0; p < 2; ++p) {
            const unsigned short* ga = A  + (size_t)(bm + p * 64 + srow) * lda + k0 + scol;
            const unsigned short* gb = Bt + (size_t)(bn + p * 64 + srow) * ldb + k0 + scol;
            gld16(ga, smA + p * 2048 + wave * 512);
            gld16(gb, smB + p * 2048 + wave * 512);
        }
        __syncthreads();
        bf16x8 af[4], bf[4];
        #pragma unroll
        for (int i = 0; i < 4; ++i) {
            af[i] = *(const bf16x8*)(smA + (wm + i * 16 + lr) * 32 + lk);
            bf[i] = *(const bf16x8*)(smB + (wn + i * 16 + lr) * 32 + lk);
        }
        #pragma unroll
        for (int mi = 0; mi < 4; ++mi)
            #pragma unroll
            for (int ni = 0; ni < 4; ++ni)
                acc[mi][ni] = __builtin_amdgcn_mfma_f32_16x16x32_bf16(af[mi], bf[ni], acc[mi][ni], 0, 0, 0);
        __syncthreads();
    }

    #pragma unroll
    for (int mi = 0; mi < 4; ++mi) {
        #pragma unroll
        for (int ni = 0; ni < 4; ++ni) {
            int c = bn + wn + ni * 16 + lr;
            #pragma unroll
            for (int v = 0; v < 4; ++v) {
                int r = bm + wm + mi * 16 + ((lane >> 4) << 2) + v;
                float val = acc[mi][ni][v];
                if (EPI == 1) {
                    val += bias[c];
                    val = (val > 20.f) ? val : log1pf(__expf(val));
                }
                C[(size_t)r * ldc + c] = val;
            }
        }
    }
}

// ---------------- causal depthwise conv (width 4) + SiLU ----------------
__global__ __launch_bounds__(256) void k_conv(const float* __restrict__ uz,
                                              const float* __restrict__ cw,
                                              const float* __restrict__ cb,
                                              float* __restrict__ uc,
                                              unsigned short* __restrict__ ucb) {
    int idx = blockIdx.x * 256 + threadIdx.x;   // over (b*L+l)*2048 + e
    int e  = idx & 2047;
    int bl = idx >> 11;
    int l  = bl & 1023;
    float acc = cb[e];
    const float* w = cw + e * 4;
    #pragma unroll
    for (int k = 0; k < 4; ++k) {
        int ls = l - 3 + k;
        if (ls >= 0) acc += w[k] * uz[(size_t)(bl - 3 + k) * 4096 + e];
    }
    float s = silu(acc);
    uc[idx]  = s;
    ucb[idx] = f2bf(s);
}

// ---------------- dbl[:, :64] -> bf16 ----------------
__global__ __launch_bounds__(256) void k_cvt_dtr(const float* __restrict__ dbl,
                                                 unsigned short* __restrict__ dtr) {
    int idx = blockIdx.x * 256 + threadIdx.x;   // 2048*64
    int r = idx >> 6, c = idx & 63;
    dtr[idx] = f2bf(dbl[(size_t)r * 128 + c]);
}

// ---------------- chunked selective scan ----------------
// L=1024 split into NC=16 chunks of CH=64.
// Layouts: dt/uc/yg [b*1024+l][2048]; dbl [b*1024+l][128] (B at +64, C at +80);
// z inside uz at [b*1024+l][4096]+2048.
// agg/hinit layout: [b][chunk][e][n] -> ((b*16+c)*2048+e)*16+n

// Pass 1: per-chunk aggregates (aprod, hloc) starting from h=0.
__global__ __launch_bounds__(256) void k_scan_p1(const float* __restrict__ dt,
                                                 const float* __restrict__ uc,
                                                 const float* __restrict__ dbl,
                                                 const float* __restrict__ A_log,
                                                 float* __restrict__ aggA,
                                                 float* __restrict__ aggH) {
    int bid = blockIdx.x;                // 2*128*16
    int c  = bid & 15;
    int eb = (bid >> 4) & 127;
    int b  = bid >> 11;
    int g = threadIdx.x >> 4, n = threadIdx.x & 15;
    int e = eb * 16 + g;
    float Aen = -__expf(A_log[e * 16 + n]);
    float h = 0.f, ap = 1.f;
    size_t base2 = ((size_t)b * 1024 + c * 64) * 2048 + e;
    size_t based = ((size_t)b * 1024 + c * 64) * 128;
    #pragma unroll 4
    for (int l = 0; l < 64; ++l) {
        float dtv = dt[base2];
        float ucv = uc[base2];
        float Bn  = dbl[based + 64 + n];
        float a   = __expf(dtv * Aen);
        h  = fmaf(a, h, dtv * ucv * Bn);
        ap *= a;
        base2 += 2048; based += 128;
    }
    size_t o = ((size_t)(b * 16 + c) * 2048 + e) * 16 + n;
    aggA[o] = ap;
    aggH[o] = h;
}

// Pass 2: scan chunk aggregates -> initial h per chunk.
__global__ __launch_bounds__(256) void k_scan_p2(const float* __restrict__ aggA,
                                                 const float* __restrict__ aggH,
                                                 float* __restrict__ hinit) {
    int t = blockIdx.x * 256 + threadIdx.x;   // b*32768 + e*16 + n  (2*2048*16)
    int b = t >> 15;
    int en = t & 32767;
    float h = 0.f;
    size_t base = (size_t)b * 16 * 32768 + en;
    #pragma unroll
    for (int c = 0; c < 16; ++c) {
        hinit[base] = h;
        h = fmaf(aggA[base], h, aggH[base]);
        base += 32768;
    }
}

// Pass 3: re-run chunk from hinit, reduce over n, skip+gate, bf16 store.
__global__ __launch_bounds__(256) void k_scan_p3(const float* __restrict__ dt,
                                                 const float* __restrict__ uc,
                                                 const float* __restrict__ dbl,
                                                 const float* __restrict__ uz,
                                                 const float* __restrict__ A_log,
                                                 const float* __restrict__ D_skip,
                                                 const float* __restrict__ hinit,
                                                 unsigned short* __restrict__ yg) {
    int bid = blockIdx.x;
    int c  = bid & 15;
    int eb = (bid >> 4) & 127;
    int b  = bid >> 11;
    int g = threadIdx.x >> 4, n = threadIdx.x & 15;
    int e = eb * 16 + g;
    float Aen = -__expf(A_log[e * 16 + n]);
    float De  = D_skip[e];
    float h = hinit[((size_t)(b * 16 + c) * 2048 + e) * 16 + n];
    size_t base2 = ((size_t)b * 1024 + c * 64) * 2048 + e;
    size_t base4 = ((size_t)b * 1024 + c * 64) * 4096 + 2048 + e;
    size_t based = ((size_t)b * 1024 + c * 64) * 128;
    #pragma unroll 4
    for (int l = 0; l < 64; ++l) {
        float dtv = dt[base2];
        float ucv = uc[base2];
        float Bn  = dbl[based + 64 + n];
        float Cn  = dbl[based + 80 + n];
        float zv  = uz[base4];
        float a   = __expf(dtv * Aen);
        h = fmaf(a, h, dtv * ucv * Bn);
        float p = h * Cn;
        p += __shfl_xor(p, 8, 16);
        p += __shfl_xor(p, 4, 16);
        p += __shfl_xor(p, 2, 16);
        p += __shfl_xor(p, 1, 16);
        if (n == 0) {
            float yv = (p + ucv * De) * silu(zv);
            yg[base2] = f2bf(yv);
        }
        base2 += 2048; base4 += 4096; based += 128;
    }
}

// ---------------- launch ----------------
extern "C" void kernel_launch(void* const* d_in, const int* in_sizes, int n_in,
                              void* d_out, int out_size, void* d_ws, size_t ws_size,
                              hipStream_t stream) {
    const float* x      = (const float*)d_in[0];
    const float* ln_g   = (const float*)d_in[1];
    const float* ln_b   = (const float*)d_in[2];
    const float* W_in   = (const float*)d_in[3];
    const float* conv_w = (const float*)d_in[4];
    const float* conv_b = (const float*)d_in[5];
    const float* W_x    = (const float*)d_in[6];
    const float* W_dt   = (const float*)d_in[7];
    const float* b_dt   = (const float*)d_in[8];
    const float* A_log  = (const float*)d_in[9];
    const float* D_skip = (const float*)d_in[10];
    const float* W_out  = (const float*)d_in[11];
    float* out = (float*)d_out;

    const size_t needed =
        (size_t)4096 * 1024 * 2 + (size_t)1024 * 2048 * 2 + (size_t)2048 * 64 * 2 +
        (size_t)128 * 2048 * 2 + (size_t)2048 * 1024 * 2 + (size_t)2048 * 4096 * 4 +
        (size_t)2048 * 2048 * 4 + (size_t)2048 * 2048 * 2 + (size_t)2048 * 128 * 4 +
        (size_t)2048 * 64 * 2 + (size_t)2048 * 2048 * 4 + (size_t)2048 * 2048 * 2;
    if (ws_size < needed) return;

    char* w = (char*)d_ws;
    unsigned short* WIN_T  = (unsigned short*)w; w += (size_t)4096 * 1024 * 2;
    unsigned short* WOUT_T = (unsigned short*)w; w += (size_t)1024 * 2048 * 2;
    unsigned short* WDT_T  = (unsigned short*)w; w += (size_t)2048 * 64 * 2;
    unsigned short* WX_T   = (unsigned short*)w; w += (size_t)128 * 2048 * 2;
    unsigned short* XN     = (unsigned short*)w; w += (size_t)2048 * 1024 * 2;
    float*          UZ     = (float*)w;          w += (size_t)2048 * 4096 * 4;
    float*          UC     = (float*)w;          w += (size_t)2048 * 2048 * 4;
    unsigned short* UCB    = (unsigned short*)w; w += (size_t)2048 * 2048 * 2;
    float*          DBL    = (float*)w;          w += (size_t)2048 * 128 * 4;
    unsigned short* DTR    = (unsigned short*)w; w += (size_t)2048 * 64 * 2;
    float*          DT     = (float*)w;          w += (size_t)2048 * 2048 * 4;
    unsigned short* YG     = (unsigned short*)w; w += (size_t)2048 * 2048 * 2;

    // scan scratch aliased onto buffers dead by scan time:
    // aggA -> XN (4MB), aggH -> WIN_T[0:4MB), hinit -> WIN_T[4MB:8MB)
    float* AGGA  = (float*)XN;
    float* AGGH  = (float*)WIN_T;
    float* HINIT = (float*)((char*)WIN_T + (size_t)4 * 1024 * 1024);

    // weight prep (transpose + bf16)
    k_transpose_cvt<<<dim3(128, 32), 256, 0, stream>>>(W_in,  WIN_T,  1024, 4096, 4096);
    k_transpose_cvt<<<dim3(32, 64),  256, 0, stream>>>(W_out, WOUT_T, 2048, 1024, 1024);
    k_transpose_cvt<<<dim3(64, 2),   256, 0, stream>>>(W_dt,  WDT_T,  64,   2048, 2048);
    k_transpose_cvt<<<dim3(4, 64),   256, 0, stream>>>(W_x,   WX_T,   2048, 96,   128);

    k_ln<<<2048, 256, 0, stream>>>(x, ln_g, ln_b, XN);

    // u,z = xn @ W_in   (2048x4096, K=1024)
    k_gemm<0><<<dim3(16, 32), 256, 0, stream>>>(XN, WIN_T, UZ, 1024, 1024, 1024, 4096, nullptr);

    k_conv<<<16384, 256, 0, stream>>>(UZ, conv_w, conv_b, UC, UCB);

    // dbl = uc @ W_x(padded)   (2048x128, K=2048)
    k_gemm<0><<<dim3(16, 1), 256, 0, stream>>>(UCB, WX_T, DBL, 2048, 2048, 2048, 128, nullptr);

    k_cvt_dtr<<<512, 256, 0, stream>>>(DBL, DTR);

    // dt = softplus(dtr @ W_dt + b_dt)   (2048x2048, K=64)
    k_gemm<1><<<dim3(16, 16), 256, 0, stream>>>(DTR, WDT_T, DT, 64, 64, 64, 2048, b_dt);

    // chunked scan (NC=16 chunks of CH=64)
    k_scan_p1<<<4096, 256, 0, stream>>>(DT, UC, DBL, A_log, AGGA, AGGH);
    k_scan_p2<<<256, 256, 0, stream>>>(AGGA, AGGH, HINIT);
    k_scan_p3<<<4096, 256, 0, stream>>>(DT, UC, DBL, UZ, A_log, D_skip, HINIT, YG);

    // out = yg @ W_out   (2048x1024, K=2048)
    k_gemm<0><<<dim3(16, 8), 256, 0, stream>>>(YG, WOUT_T, out, 2048, 2048, 2048, 1024, nullptr);
}

// Round 4
// 337.265 us; speedup vs baseline: 3.0130x; 1.2173x over previous
//
#include <hip/hip_runtime.h>
#include <hip/hip_bf16.h>

// ---------------- types & helpers ----------------
typedef __attribute__((ext_vector_type(4))) float  f32x4;
typedef __attribute__((ext_vector_type(8))) __bf16 bf16x8;

typedef __attribute__((address_space(1))) void gvoid_t;
typedef __attribute__((address_space(3))) void lvoid_t;

__device__ __forceinline__ void gld16(const void* g, void* l) {
    // async global->LDS, 16B per lane; LDS dest = wave-uniform base + lane*16
    __builtin_amdgcn_global_load_lds((const gvoid_t*)g, (lvoid_t*)l, 16, 0, 0);
}

__device__ __forceinline__ unsigned short f2bf(float f) {
    unsigned u = __builtin_bit_cast(unsigned, f);
    u += 0x7fffu + ((u >> 16) & 1u);
    return (unsigned short)(u >> 16);
}

__device__ __forceinline__ float silu(float x) {
    return x / (1.f + __expf(-x));
}

// ---------------- weight transpose + fp32->bf16 ----------------
// in: K x N fp32 (row-major). out: Npad x K bf16 (row-major), rows n>=N are zero.
__global__ __launch_bounds__(256) void k_transpose_cvt(const float* __restrict__ in,
                                                       unsigned short* __restrict__ out,
                                                       int K, int N, int Npad) {
    __shared__ float t[32][33];
    int bn = blockIdx.x * 32;   // over N (output rows)
    int bk = blockIdx.y * 32;   // over K
    int c = threadIdx.x & 31, r0 = threadIdx.x >> 5;   // 8 rows per pass
    #pragma unroll
    for (int rr = r0; rr < 32; rr += 8) {
        int k = bk + rr, n = bn + c;
        t[rr][c] = (k < K && n < N) ? in[(size_t)k * N + n] : 0.f;
    }
    __syncthreads();
    #pragma unroll
    for (int rr = r0; rr < 32; rr += 8) {
        int n = bn + rr, k = bk + c;
        if (n < Npad && k < K) out[(size_t)n * K + k] = f2bf(t[c][rr]);
    }
}

// ---------------- LayerNorm -> bf16 ----------------
__global__ __launch_bounds__(256) void k_ln(const float* __restrict__ x,
                                            const float* __restrict__ g,
                                            const float* __restrict__ b,
                                            unsigned short* __restrict__ xn) {
    int row = blockIdx.x;                       // 0..2047 (b*L+l)
    const float4* xr = (const float4*)(x + (size_t)row * 1024);
    float4 v = xr[threadIdx.x];
    float s  = v.x + v.y + v.z + v.w;
    float ss = v.x*v.x + v.y*v.y + v.z*v.z + v.w*v.w;
    #pragma unroll
    for (int o = 32; o > 0; o >>= 1) { s += __shfl_down(s, o); ss += __shfl_down(ss, o); }
    __shared__ float red[8];
    if ((threadIdx.x & 63) == 0) { red[threadIdx.x >> 6] = s; red[4 + (threadIdx.x >> 6)] = ss; }
    __syncthreads();
    s  = red[0] + red[1] + red[2] + red[3];
    ss = red[4] + red[5] + red[6] + red[7];
    float mu  = s * (1.f / 1024.f);
    float inv = rsqrtf(ss * (1.f / 1024.f) - mu * mu + 1e-5f);
    float4 gv = ((const float4*)g)[threadIdx.x];
    float4 bv = ((const float4*)b)[threadIdx.x];
    ushort4 o4;
    o4.x = f2bf((v.x - mu) * inv * gv.x + bv.x);
    o4.y = f2bf((v.y - mu) * inv * gv.y + bv.y);
    o4.z = f2bf((v.z - mu) * inv * gv.z + bv.z);
    o4.w = f2bf((v.w - mu) * inv * gv.w + bv.w);
    ((ushort4*)xn)[(size_t)row * 256 + threadIdx.x] = o4;
}

// ---------------- generic bf16 MFMA GEMM ----------------
// C(MxN fp32,ldc) = A(MxK bf16 row-major,lda) @ Bt(NxK bf16 row-major,ldb)^T
// block tile 128x128, BK=32, 4 waves (2x2), each wave 64x64 = 4x4 frags of 16x16.
// M,N multiples of 128; K multiple of 32. EPI: 0=none, 1=softplus(x+bias[col])
template <int EPI>
__global__ __launch_bounds__(256) void k_gemm(const unsigned short* __restrict__ A,
                                              const unsigned short* __restrict__ Bt,
                                              float* __restrict__ C,
                                              int K, int lda, int ldb, int ldc,
                                              const float* __restrict__ bias) {
    __shared__ __attribute__((aligned(16))) unsigned short smA[128 * 32];
    __shared__ __attribute__((aligned(16))) unsigned short smB[128 * 32];

    int tid  = threadIdx.x;
    int wave = tid >> 6, lane = tid & 63;
    int bm = blockIdx.x * 128, bn = blockIdx.y * 128;
    int wm = (wave >> 1) * 64, wn = (wave & 1) * 64;
    int lr = lane & 15, lk = (lane >> 4) * 8;

    int srow = tid >> 2;            // 0..63  (+ p*64)
    int scol = (tid & 3) << 3;      // 0,8,16,24

    f32x4 acc[4][4] = {};

    for (int k0 = 0; k0 < K; k0 += 32) {
        #pragma unroll
        for (int p = 0; p < 2; ++p) {
            const unsigned short* ga = A  + (size_t)(bm + p * 64 + srow) * lda + k0 + scol;
            const unsigned short* gb = Bt + (size_t)(bn + p * 64 + srow) * ldb + k0 + scol;
            gld16(ga, smA + p * 2048 + wave * 512);
            gld16(gb, smB + p * 2048 + wave * 512);
        }
        __syncthreads();
        bf16x8 af[4], bf[4];
        #pragma unroll
        for (int i = 0; i < 4; ++i) {
            af[i] = *(const bf16x8*)(smA + (wm + i * 16 + lr) * 32 + lk);
            bf[i] = *(const bf16x8*)(smB + (wn + i * 16 + lr) * 32 + lk);
        }
        #pragma unroll
        for (int mi = 0; mi < 4; ++mi)
            #pragma unroll
            for (int ni = 0; ni < 4; ++ni)
                acc[mi][ni] = __builtin_amdgcn_mfma_f32_16x16x32_bf16(af[mi], bf[ni], acc[mi][ni], 0, 0, 0);
        __syncthreads();
    }

    #pragma unroll
    for (int mi = 0; mi < 4; ++mi) {
        #pragma unroll
        for (int ni = 0; ni < 4; ++ni) {
            int c = bn + wn + ni * 16 + lr;
            #pragma unroll
            for (int v = 0; v < 4; ++v) {
                int r = bm + wm + mi * 16 + ((lane >> 4) << 2) + v;
                float val = acc[mi][ni][v];
                if (EPI == 1) {
                    val += bias[c];
                    val = (val > 20.f) ? val : log1pf(__expf(val));
                }
                C[(size_t)r * ldc + c] = val;
            }
        }
    }
}

// ---------------- causal depthwise conv (width 4) + SiLU ----------------
__global__ __launch_bounds__(256) void k_conv(const float* __restrict__ uz,
                                              const float* __restrict__ cw,
                                              const float* __restrict__ cb,
                                              float* __restrict__ uc,
                                              unsigned short* __restrict__ ucb) {
    int idx = blockIdx.x * 256 + threadIdx.x;   // over (b*L+l)*2048 + e
    int e  = idx & 2047;
    int bl = idx >> 11;
    int l  = bl & 1023;
    float acc = cb[e];
    const float* w = cw + e * 4;
    #pragma unroll
    for (int k = 0; k < 4; ++k) {
        int ls = l - 3 + k;
        if (ls >= 0) acc += w[k] * uz[(size_t)(bl - 3 + k) * 4096 + e];
    }
    float s = silu(acc);
    uc[idx]  = s;
    ucb[idx] = f2bf(s);
}

// ---------------- dbl[:, :64] -> bf16 ----------------
__global__ __launch_bounds__(256) void k_cvt_dtr(const float* __restrict__ dbl,
                                                 unsigned short* __restrict__ dtr) {
    int idx = blockIdx.x * 256 + threadIdx.x;   // 2048*64
    int r = idx >> 6, c = idx & 63;
    dtr[idx] = f2bf(dbl[(size_t)r * 128 + c]);
}

// ---------------- chunked selective scan, lane-owns-element ----------------
// L=1024 -> 16 chunks of 64. Each thread owns one e with all 16 states in regs.
// dt/uc/yg [b*1024+l][2048]; dbl [b*1024+l][128] (B at +64, C at +80);
// z at uz[b*1024+l][4096]+2048.
// agg/hinit layout: ((b*16+c)*16 + n)*2048 + e   (n-major -> coalesced over e)

// Pass 1: per-chunk aggregates (Pi a = exp(Aen*sum dt), h_local from h=0).
__global__ __launch_bounds__(256) void k_scan_p1(const float* __restrict__ dt,
                                                 const float* __restrict__ uc,
                                                 const float* __restrict__ dbl,
                                                 const float* __restrict__ A_log,
                                                 float* __restrict__ aggA,
                                                 float* __restrict__ aggH) {
    __shared__ float sBC[64][32];
    int bid = blockIdx.x;
    int c = bid & 15, eblk = (bid >> 4) & 7, b = bid >> 7;
    int t = threadIdx.x;
    int e = eblk * 256 + t;
    int bl0 = b * 1024 + c * 64;
    #pragma unroll
    for (int i = t; i < 512; i += 256) {      // stage B,C: dbl[.., 64..96)
        int r = i >> 3, j = i & 7;
        *(float4*)&sBC[r][j * 4] = *(const float4*)(dbl + (size_t)(bl0 + r) * 128 + 64 + j * 4);
    }
    __syncthreads();
    float Aen[16];
    #pragma unroll
    for (int n = 0; n < 16; ++n) Aen[n] = -__expf(A_log[e * 16 + n]);
    bool fastA = true;
    #pragma unroll
    for (int n = 1; n < 16; ++n)
        fastA = fastA && (fabsf(Aen[n] - (n + 1) * Aen[0]) <= 1e-3f);
    float h[16];
    #pragma unroll
    for (int n = 0; n < 16; ++n) h[n] = 0.f;
    float sdt = 0.f;
    size_t idx2 = (size_t)bl0 * 2048 + e;
    #pragma unroll 4
    for (int l = 0; l < 64; ++l) {
        float dtv = dt[idx2], ucv = uc[idx2];
        float dtu = dtv * ucv;
        float dA[16];
        if (fastA) {
            float p = __expf(dtv * Aen[0]);
            float cur = p;
            #pragma unroll
            for (int n = 0; n < 16; ++n) { dA[n] = cur; cur *= p; }
        } else {
            #pragma unroll
            for (int n = 0; n < 16; ++n) dA[n] = __expf(dtv * Aen[n]);
        }
        #pragma unroll
        for (int n = 0; n < 16; ++n)
            h[n] = fmaf(dA[n], h[n], dtu * sBC[l][n]);
        sdt += dtv;
        idx2 += 2048;
    }
    size_t o = ((size_t)(b * 16 + c) * 16) * 2048 + e;
    #pragma unroll
    for (int n = 0; n < 16; ++n) {
        aggA[o + (size_t)n * 2048] = __expf(sdt * Aen[n]);
        aggH[o + (size_t)n * 2048] = h[n];
    }
}

// Pass 2: scan the 16 chunk aggregates -> initial h per chunk.
__global__ __launch_bounds__(256) void k_scan_p2(const float* __restrict__ aggA,
                                                 const float* __restrict__ aggH,
                                                 float* __restrict__ hinit) {
    int bid = blockIdx.x;                     // 2*16*8
    int b = bid >> 7, n = (bid >> 3) & 15, eblk = bid & 7;
    int e = eblk * 256 + threadIdx.x;
    float h = 0.f;
    #pragma unroll
    for (int c = 0; c < 16; ++c) {
        size_t base = ((size_t)(b * 16 + c) * 16 + n) * 2048 + e;
        hinit[base] = h;
        h = fmaf(aggA[base], h, aggH[base]);
    }
}

// Pass 3: re-run chunk from hinit, y = sum_n h*C + skip, gate, bf16 store.
__global__ __launch_bounds__(256) void k_scan_p3(const float* __restrict__ dt,
                                                 const float* __restrict__ uc,
                                                 const float* __restrict__ dbl,
                                                 const float* __restrict__ uz,
                                                 const float* __restrict__ A_log,
                                                 const float* __restrict__ D_skip,
                                                 const float* __restrict__ hinit,
                                                 unsigned short* __restrict__ yg) {
    __shared__ float sBC[64][32];
    int bid = blockIdx.x;
    int c = bid & 15, eblk = (bid >> 4) & 7, b = bid >> 7;
    int t = threadIdx.x;
    int e = eblk * 256 + t;
    int bl0 = b * 1024 + c * 64;
    #pragma unroll
    for (int i = t; i < 512; i += 256) {
        int r = i >> 3, j = i & 7;
        *(float4*)&sBC[r][j * 4] = *(const float4*)(dbl + (size_t)(bl0 + r) * 128 + 64 + j * 4);
    }
    __syncthreads();
    float Aen[16];
    #pragma unroll
    for (int n = 0; n < 16; ++n) Aen[n] = -__expf(A_log[e * 16 + n]);
    bool fastA = true;
    #pragma unroll
    for (int n = 1; n < 16; ++n)
        fastA = fastA && (fabsf(Aen[n] - (n + 1) * Aen[0]) <= 1e-3f);
    float De = D_skip[e];
    size_t o = ((size_t)(b * 16 + c) * 16) * 2048 + e;
    float h[16];
    #pragma unroll
    for (int n = 0; n < 16; ++n) h[n] = hinit[o + (size_t)n * 2048];
    size_t idx2 = (size_t)bl0 * 2048 + e;
    size_t idx4 = (size_t)bl0 * 4096 + 2048 + e;
    #pragma unroll 4
    for (int l = 0; l < 64; ++l) {
        float dtv = dt[idx2], ucv = uc[idx2];
        float zv  = uz[idx4];
        float dtu = dtv * ucv;
        float dA[16];
        if (fastA) {
            float p = __expf(dtv * Aen[0]);
            float cur = p;
            #pragma unroll
            for (int n = 0; n < 16; ++n) { dA[n] = cur; cur *= p; }
        } else {
            #pragma unroll
            for (int n = 0; n < 16; ++n) dA[n] = __expf(dtv * Aen[n]);
        }
        float y = 0.f;
        #pragma unroll
        for (int n = 0; n < 16; ++n) {
            h[n] = fmaf(dA[n], h[n], dtu * sBC[l][n]);
            y = fmaf(h[n], sBC[l][16 + n], y);
        }
        y = (y + ucv * De) * silu(zv);
        yg[idx2] = f2bf(y);
        idx2 += 2048; idx4 += 4096;
    }
}

// ---------------- launch ----------------
extern "C" void kernel_launch(void* const* d_in, const int* in_sizes, int n_in,
                              void* d_out, int out_size, void* d_ws, size_t ws_size,
                              hipStream_t stream) {
    const float* x      = (const float*)d_in[0];
    const float* ln_g   = (const float*)d_in[1];
    const float* ln_b   = (const float*)d_in[2];
    const float* W_in   = (const float*)d_in[3];
    const float* conv_w = (const float*)d_in[4];
    const float* conv_b = (const float*)d_in[5];
    const float* W_x    = (const float*)d_in[6];
    const float* W_dt   = (const float*)d_in[7];
    const float* b_dt   = (const float*)d_in[8];
    const float* A_log  = (const float*)d_in[9];
    const float* D_skip = (const float*)d_in[10];
    const float* W_out  = (const float*)d_in[11];
    float* out = (float*)d_out;

    const size_t needed =
        (size_t)4096 * 1024 * 2 + (size_t)1024 * 2048 * 2 + (size_t)2048 * 64 * 2 +
        (size_t)128 * 2048 * 2 + (size_t)2048 * 1024 * 2 + (size_t)2048 * 4096 * 4 +
        (size_t)2048 * 2048 * 4 + (size_t)2048 * 2048 * 2 + (size_t)2048 * 128 * 4 +
        (size_t)2048 * 64 * 2 + (size_t)2048 * 2048 * 4 + (size_t)2048 * 2048 * 2;
    if (ws_size < needed) return;

    char* w = (char*)d_ws;
    unsigned short* WIN_T  = (unsigned short*)w; w += (size_t)4096 * 1024 * 2;
    unsigned short* WOUT_T = (unsigned short*)w; w += (size_t)1024 * 2048 * 2;
    unsigned short* WDT_T  = (unsigned short*)w; w += (size_t)2048 * 64 * 2;
    unsigned short* WX_T   = (unsigned short*)w; w += (size_t)128 * 2048 * 2;
    unsigned short* XN     = (unsigned short*)w; w += (size_t)2048 * 1024 * 2;
    float*          UZ     = (float*)w;          w += (size_t)2048 * 4096 * 4;
    float*          UC     = (float*)w;          w += (size_t)2048 * 2048 * 4;
    unsigned short* UCB    = (unsigned short*)w; w += (size_t)2048 * 2048 * 2;
    float*          DBL    = (float*)w;          w += (size_t)2048 * 128 * 4;
    unsigned short* DTR    = (unsigned short*)w; w += (size_t)2048 * 64 * 2;
    float*          DT     = (float*)w;          w += (size_t)2048 * 2048 * 4;
    unsigned short* YG     = (unsigned short*)w; w += (size_t)2048 * 2048 * 2;

    // scan scratch aliased onto buffers dead by scan time:
    // aggA -> XN (4MB), aggH -> WIN_T[0:4MB), hinit -> WIN_T[4MB:8MB)
    float* AGGA  = (float*)XN;
    float* AGGH  = (float*)WIN_T;
    float* HINIT = (float*)((char*)WIN_T + (size_t)4 * 1024 * 1024);

    // weight prep (transpose + bf16)
    k_transpose_cvt<<<dim3(128, 32), 256, 0, stream>>>(W_in,  WIN_T,  1024, 4096, 4096);
    k_transpose_cvt<<<dim3(32, 64),  256, 0, stream>>>(W_out, WOUT_T, 2048, 1024, 1024);
    k_transpose_cvt<<<dim3(64, 2),   256, 0, stream>>>(W_dt,  WDT_T,  64,   2048, 2048);
    k_transpose_cvt<<<dim3(4, 64),   256, 0, stream>>>(W_x,   WX_T,   2048, 96,   128);

    k_ln<<<2048, 256, 0, stream>>>(x, ln_g, ln_b, XN);

    // u,z = xn @ W_in   (2048x4096, K=1024)
    k_gemm<0><<<dim3(16, 32), 256, 0, stream>>>(XN, WIN_T, UZ, 1024, 1024, 1024, 4096, nullptr);

    k_conv<<<16384, 256, 0, stream>>>(UZ, conv_w, conv_b, UC, UCB);

    // dbl = uc @ W_x(padded)   (2048x128, K=2048)
    k_gemm<0><<<dim3(16, 1), 256, 0, stream>>>(UCB, WX_T, DBL, 2048, 2048, 2048, 128, nullptr);

    k_cvt_dtr<<<512, 256, 0, stream>>>(DBL, DTR);

    // dt = softplus(dtr @ W_dt + b_dt)   (2048x2048, K=64)
    k_gemm<1><<<dim3(16, 16), 256, 0, stream>>>(DTR, WDT_T, DT, 64, 64, 64, 2048, b_dt);

    // chunked scan (16 chunks of 64, lane-owns-element)
    k_scan_p1<<<256, 256, 0, stream>>>(DT, UC, DBL, A_log, AGGA, AGGH);
    k_scan_p2<<<256, 256, 0, stream>>>(AGGA, AGGH, HINIT);
    k_scan_p3<<<256, 256, 0, stream>>>(DT, UC, DBL, UZ, A_log, D_skip, HINIT, YG);

    // out = yg @ W_out   (2048x1024, K=2048)
    k_gemm<0><<<dim3(16, 8), 256, 0, stream>>>(YG, WOUT_T, out, 2048, 2048, 2048, 1024, nullptr);
}

// Round 5
// 285.006 us; speedup vs baseline: 3.5655x; 1.1834x over previous
//
#include <hip/hip_runtime.h>
#include <hip/hip_bf16.h>

// ---------------- types & helpers ----------------
typedef __attribute__((ext_vector_type(4))) float  f32x4;
typedef __attribute__((ext_vector_type(8))) __bf16 bf16x8;

typedef __attribute__((address_space(1))) void gvoid_t;
typedef __attribute__((address_space(3))) void lvoid_t;

__device__ __forceinline__ void gld16(const void* g, void* l) {
    // async global->LDS, 16B per lane; LDS dest = wave-uniform base + lane*16
    __builtin_amdgcn_global_load_lds((const gvoid_t*)g, (lvoid_t*)l, 16, 0, 0);
}

template <int N> __device__ __forceinline__ void vwait() {
    if constexpr (N == 0)      asm volatile("s_waitcnt vmcnt(0)" ::: "memory");
    else if constexpr (N == 6) asm volatile("s_waitcnt vmcnt(6)" ::: "memory");
    else if constexpr (N == 8) asm volatile("s_waitcnt vmcnt(8)" ::: "memory");
}

__device__ __forceinline__ unsigned short f2bf(float f) {
    unsigned u = __builtin_bit_cast(unsigned, f);
    u += 0x7fffu + ((u >> 16) & 1u);
    return (unsigned short)(u >> 16);
}

__device__ __forceinline__ float silu(float x) {
    return x / (1.f + __expf(-x));
}

// ---------------- weight transpose + fp32->bf16 ----------------
__global__ __launch_bounds__(256) void k_transpose_cvt(const float* __restrict__ in,
                                                       unsigned short* __restrict__ out,
                                                       int K, int N, int Npad) {
    __shared__ float t[32][33];
    int bn = blockIdx.x * 32;
    int bk = blockIdx.y * 32;
    int c = threadIdx.x & 31, r0 = threadIdx.x >> 5;
    #pragma unroll
    for (int rr = r0; rr < 32; rr += 8) {
        int k = bk + rr, n = bn + c;
        t[rr][c] = (k < K && n < N) ? in[(size_t)k * N + n] : 0.f;
    }
    __syncthreads();
    #pragma unroll
    for (int rr = r0; rr < 32; rr += 8) {
        int n = bn + rr, k = bk + c;
        if (n < Npad && k < K) out[(size_t)n * K + k] = f2bf(t[c][rr]);
    }
}

// ---------------- LayerNorm -> bf16 ----------------
__global__ __launch_bounds__(256) void k_ln(const float* __restrict__ x,
                                            const float* __restrict__ g,
                                            const float* __restrict__ b,
                                            unsigned short* __restrict__ xn) {
    int row = blockIdx.x;
    const float4* xr = (const float4*)(x + (size_t)row * 1024);
    float4 v = xr[threadIdx.x];
    float s  = v.x + v.y + v.z + v.w;
    float ss = v.x*v.x + v.y*v.y + v.z*v.z + v.w*v.w;
    #pragma unroll
    for (int o = 32; o > 0; o >>= 1) { s += __shfl_down(s, o); ss += __shfl_down(ss, o); }
    __shared__ float red[8];
    if ((threadIdx.x & 63) == 0) { red[threadIdx.x >> 6] = s; red[4 + (threadIdx.x >> 6)] = ss; }
    __syncthreads();
    s  = red[0] + red[1] + red[2] + red[3];
    ss = red[4] + red[5] + red[6] + red[7];
    float mu  = s * (1.f / 1024.f);
    float inv = rsqrtf(ss * (1.f / 1024.f) - mu * mu + 1e-5f);
    float4 gv = ((const float4*)g)[threadIdx.x];
    float4 bv = ((const float4*)b)[threadIdx.x];
    ushort4 o4;
    o4.x = f2bf((v.x - mu) * inv * gv.x + bv.x);
    o4.y = f2bf((v.y - mu) * inv * gv.y + bv.y);
    o4.z = f2bf((v.z - mu) * inv * gv.z + bv.z);
    o4.w = f2bf((v.w - mu) * inv * gv.w + bv.w);
    ((ushort4*)xn)[(size_t)row * 256 + threadIdx.x] = o4;
}

// ---------------- pipelined bf16 MFMA GEMM (2-phase, BK=64, XOR-swizzled LDS) ----
// C(MxN fp32,ldc) = A(MxK bf16 rm,lda) @ Bt(NxK bf16 rm,ldb)^T  [+ split-K via z]
// Tile BM x BN, 4 waves (2x2), wave tile (BM/2)x(BN/2). kchunk per z, mult of 64.
// LDS rows are 128B; swizzle cg ^= (row&7) applied on BOTH stage-source and read.
// EPI: 0=none, 1=softplus(x+bias[col])
template <int BM, int BN, int EPI>
__global__ __launch_bounds__(256) void k_gemm2(const unsigned short* __restrict__ A,
                                               const unsigned short* __restrict__ Bt,
                                               float* __restrict__ C,
                                               int kchunk, int lda, int ldb, int ldc,
                                               size_t zstride,
                                               const float* __restrict__ bias) {
    constexpr int PA = BM / 32, PB = BN / 32, NV = PA + PB;
    constexpr int MF = BM / 32, NF = BN / 32;
    __shared__ __attribute__((aligned(16))) unsigned short smA[2 * BM * 64];
    __shared__ __attribute__((aligned(16))) unsigned short smB[2 * BN * 64];

    int tid = threadIdx.x, wave = tid >> 6, lane = tid & 63;
    int bm = blockIdx.x * BM, bn = blockIdx.y * BN;
    int kstart = blockIdx.z * kchunk;
    int nt = kchunk >> 6;
    C += (size_t)blockIdx.z * zstride;
    int wm = (wave >> 1) * (BM / 2), wn = (wave & 1) * (BN / 2);
    int lr = lane & 15, lq = lane >> 4;
    int srow = wave * 8 + (lane >> 3);   // + p*32 ; row&7 == lane>>3
    int scg  = lane & 7;

    f32x4 acc[MF][NF] = {};

    auto STAGE = [&](int buf, int k0) {
        unsigned short* dA = smA + buf * (BM * 64) + wave * 512;
        unsigned short* dB = smB + buf * (BN * 64) + wave * 512;
        #pragma unroll
        for (int p = 0; p < PA; ++p) {
            int row = p * 32 + srow;
            int gcol = ((scg ^ (row & 7)) << 3) + k0;
            gld16(A + (size_t)(bm + row) * lda + gcol, dA + p * 2048);
        }
        #pragma unroll
        for (int p = 0; p < PB; ++p) {
            int row = p * 32 + srow;
            int gcol = ((scg ^ (row & 7)) << 3) + k0;
            gld16(Bt + (size_t)(bn + row) * ldb + gcol, dB + p * 2048);
        }
    };

    STAGE(0, kstart);
    for (int t = 0; t < nt; ++t) {
        int cur = t & 1;
        if (t + 1 < nt) { STAGE(cur ^ 1, kstart + (t + 1) * 64); vwait<NV>(); }
        else            { vwait<0>(); }
        __builtin_amdgcn_s_barrier();
        const unsigned short* sA = smA + cur * (BM * 64);
        const unsigned short* sB = smB + cur * (BN * 64);
        #pragma unroll
        for (int ks = 0; ks < 2; ++ks) {
            int cg = (ks * 4 + lq) ^ (lr & 7);
            bf16x8 af[MF], bfv[NF];
            #pragma unroll
            for (int i = 0; i < MF; ++i)
                af[i] = *(const bf16x8*)(sA + (wm + i * 16 + lr) * 64 + (cg << 3));
            #pragma unroll
            for (int i = 0; i < NF; ++i)
                bfv[i] = *(const bf16x8*)(sB + (wn + i * 16 + lr) * 64 + (cg << 3));
            #pragma unroll
            for (int mi = 0; mi < MF; ++mi)
                #pragma unroll
                for (int ni = 0; ni < NF; ++ni)
                    acc[mi][ni] = __builtin_amdgcn_mfma_f32_16x16x32_bf16(af[mi], bfv[ni], acc[mi][ni], 0, 0, 0);
        }
        __builtin_amdgcn_s_barrier();
    }

    #pragma unroll
    for (int mi = 0; mi < MF; ++mi) {
        #pragma unroll
        for (int ni = 0; ni < NF; ++ni) {
            int c = bn + wn + ni * 16 + lr;
            #pragma unroll
            for (int v = 0; v < 4; ++v) {
                int r = bm + wm + mi * 16 + (lq << 2) + v;
                float val = acc[mi][ni][v];
                if (EPI == 1) {
                    val += bias[c];
                    val = (val > 20.f) ? val : log1pf(__expf(val));
                }
                C[(size_t)r * ldc + c] = val;
            }
        }
    }
}

// ---------------- split-K reduce (8 partials) + dtr bf16 ----------------
__global__ __launch_bounds__(256) void k_red8(const float* __restrict__ part,
                                              float* __restrict__ dbl,
                                              unsigned short* __restrict__ dtr) {
    int idx = blockIdx.x * 256 + threadIdx.x;   // 2048*128
    float s = 0.f;
    #pragma unroll
    for (int z = 0; z < 8; ++z) s += part[(size_t)z * 262144 + idx];
    dbl[idx] = s;
    int r = idx >> 7, c = idx & 127;
    if (c < 64) dtr[r * 64 + c] = f2bf(s);
}

// ---------------- causal depthwise conv (width 4) + SiLU ----------------
__global__ __launch_bounds__(256) void k_conv(const float* __restrict__ uz,
                                              const float* __restrict__ cw,
                                              const float* __restrict__ cb,
                                              float* __restrict__ uc,
                                              unsigned short* __restrict__ ucb) {
    int idx = blockIdx.x * 256 + threadIdx.x;
    int e  = idx & 2047;
    int bl = idx >> 11;
    int l  = bl & 1023;
    float acc = cb[e];
    const float* w = cw + e * 4;
    #pragma unroll
    for (int k = 0; k < 4; ++k) {
        int ls = l - 3 + k;
        if (ls >= 0) acc += w[k] * uz[(size_t)(bl - 3 + k) * 4096 + e];
    }
    float s = silu(acc);
    uc[idx]  = s;
    ucb[idx] = f2bf(s);
}

// ---------------- chunked selective scan, lane-owns-element ----------------
__global__ __launch_bounds__(256) void k_scan_p1(const float* __restrict__ dt,
                                                 const float* __restrict__ uc,
                                                 const float* __restrict__ dbl,
                                                 const float* __restrict__ A_log,
                                                 float* __restrict__ aggA,
                                                 float* __restrict__ aggH) {
    __shared__ float sBC[64][32];
    int bid = blockIdx.x;
    int c = bid & 15, eblk = (bid >> 4) & 7, b = bid >> 7;
    int t = threadIdx.x;
    int e = eblk * 256 + t;
    int bl0 = b * 1024 + c * 64;
    #pragma unroll
    for (int i = t; i < 512; i += 256) {
        int r = i >> 3, j = i & 7;
        *(float4*)&sBC[r][j * 4] = *(const float4*)(dbl + (size_t)(bl0 + r) * 128 + 64 + j * 4);
    }
    __syncthreads();
    float Aen[16];
    #pragma unroll
    for (int n = 0; n < 16; ++n) Aen[n] = -__expf(A_log[e * 16 + n]);
    bool fastA = true;
    #pragma unroll
    for (int n = 1; n < 16; ++n)
        fastA = fastA && (fabsf(Aen[n] - (n + 1) * Aen[0]) <= 1e-3f);
    float h[16];
    #pragma unroll
    for (int n = 0; n < 16; ++n) h[n] = 0.f;
    float sdt = 0.f;
    size_t idx2 = (size_t)bl0 * 2048 + e;
    #pragma unroll 4
    for (int l = 0; l < 64; ++l) {
        float dtv = dt[idx2], ucv = uc[idx2];
        float dtu = dtv * ucv;
        float dA[16];
        if (fastA) {
            float p = __expf(dtv * Aen[0]);
            float cur = p;
            #pragma unroll
            for (int n = 0; n < 16; ++n) { dA[n] = cur; cur *= p; }
        } else {
            #pragma unroll
            for (int n = 0; n < 16; ++n) dA[n] = __expf(dtv * Aen[n]);
        }
        #pragma unroll
        for (int n = 0; n < 16; ++n)
            h[n] = fmaf(dA[n], h[n], dtu * sBC[l][n]);
        sdt += dtv;
        idx2 += 2048;
    }
    size_t o = ((size_t)(b * 16 + c) * 16) * 2048 + e;
    #pragma unroll
    for (int n = 0; n < 16; ++n) {
        aggA[o + (size_t)n * 2048] = __expf(sdt * Aen[n]);
        aggH[o + (size_t)n * 2048] = h[n];
    }
}

__global__ __launch_bounds__(256) void k_scan_p2(const float* __restrict__ aggA,
                                                 const float* __restrict__ aggH,
                                                 float* __restrict__ hinit) {
    int bid = blockIdx.x;
    int b = bid >> 7, n = (bid >> 3) & 15, eblk = bid & 7;
    int e = eblk * 256 + threadIdx.x;
    float h = 0.f;
    #pragma unroll
    for (int c = 0; c < 16; ++c) {
        size_t base = ((size_t)(b * 16 + c) * 16 + n) * 2048 + e;
        hinit[base] = h;
        h = fmaf(aggA[base], h, aggH[base]);
    }
}

__global__ __launch_bounds__(256) void k_scan_p3(const float* __restrict__ dt,
                                                 const float* __restrict__ uc,
                                                 const float* __restrict__ dbl,
                                                 const float* __restrict__ uz,
                                                 const float* __restrict__ A_log,
                                                 const float* __restrict__ D_skip,
                                                 const float* __restrict__ hinit,
                                                 unsigned short* __restrict__ yg) {
    __shared__ float sBC[64][32];
    int bid = blockIdx.x;
    int c = bid & 15, eblk = (bid >> 4) & 7, b = bid >> 7;
    int t = threadIdx.x;
    int e = eblk * 256 + t;
    int bl0 = b * 1024 + c * 64;
    #pragma unroll
    for (int i = t; i < 512; i += 256) {
        int r = i >> 3, j = i & 7;
        *(float4*)&sBC[r][j * 4] = *(const float4*)(dbl + (size_t)(bl0 + r) * 128 + 64 + j * 4);
    }
    __syncthreads();
    float Aen[16];
    #pragma unroll
    for (int n = 0; n < 16; ++n) Aen[n] = -__expf(A_log[e * 16 + n]);
    bool fastA = true;
    #pragma unroll
    for (int n = 1; n < 16; ++n)
        fastA = fastA && (fabsf(Aen[n] - (n + 1) * Aen[0]) <= 1e-3f);
    float De = D_skip[e];
    size_t o = ((size_t)(b * 16 + c) * 16) * 2048 + e;
    float h[16];
    #pragma unroll
    for (int n = 0; n < 16; ++n) h[n] = hinit[o + (size_t)n * 2048];
    size_t idx2 = (size_t)bl0 * 2048 + e;
    size_t idx4 = (size_t)bl0 * 4096 + 2048 + e;
    #pragma unroll 4
    for (int l = 0; l < 64; ++l) {
        float dtv = dt[idx2], ucv = uc[idx2];
        float zv  = uz[idx4];
        float dtu = dtv * ucv;
        float dA[16];
        if (fastA) {
            float p = __expf(dtv * Aen[0]);
            float cur = p;
            #pragma unroll
            for (int n = 0; n < 16; ++n) { dA[n] = cur; cur *= p; }
        } else {
            #pragma unroll
            for (int n = 0; n < 16; ++n) dA[n] = __expf(dtv * Aen[n]);
        }
        float y = 0.f;
        #pragma unroll
        for (int n = 0; n < 16; ++n) {
            h[n] = fmaf(dA[n], h[n], dtu * sBC[l][n]);
            y = fmaf(h[n], sBC[l][16 + n], y);
        }
        y = (y + ucv * De) * silu(zv);
        yg[idx2] = f2bf(y);
        idx2 += 2048; idx4 += 4096;
    }
}

// ---------------- launch ----------------
extern "C" void kernel_launch(void* const* d_in, const int* in_sizes, int n_in,
                              void* d_out, int out_size, void* d_ws, size_t ws_size,
                              hipStream_t stream) {
    const float* x      = (const float*)d_in[0];
    const float* ln_g   = (const float*)d_in[1];
    const float* ln_b   = (const float*)d_in[2];
    const float* W_in   = (const float*)d_in[3];
    const float* conv_w = (const float*)d_in[4];
    const float* conv_b = (const float*)d_in[5];
    const float* W_x    = (const float*)d_in[6];
    const float* W_dt   = (const float*)d_in[7];
    const float* b_dt   = (const float*)d_in[8];
    const float* A_log  = (const float*)d_in[9];
    const float* D_skip = (const float*)d_in[10];
    const float* W_out  = (const float*)d_in[11];
    float* out = (float*)d_out;

    const size_t needed =
        (size_t)4096 * 1024 * 2 + (size_t)1024 * 2048 * 2 + (size_t)2048 * 64 * 2 +
        (size_t)128 * 2048 * 2 + (size_t)2048 * 1024 * 2 + (size_t)2048 * 4096 * 4 +
        (size_t)2048 * 2048 * 4 + (size_t)2048 * 2048 * 2 + (size_t)2048 * 128 * 4 +
        (size_t)2048 * 64 * 2 + (size_t)2048 * 2048 * 4 + (size_t)2048 * 2048 * 2;
    if (ws_size < needed) return;

    char* w = (char*)d_ws;
    unsigned short* WIN_T  = (unsigned short*)w; w += (size_t)4096 * 1024 * 2;
    unsigned short* WOUT_T = (unsigned short*)w; w += (size_t)1024 * 2048 * 2;
    unsigned short* WDT_T  = (unsigned short*)w; w += (size_t)2048 * 64 * 2;
    unsigned short* WX_T   = (unsigned short*)w; w += (size_t)128 * 2048 * 2;
    unsigned short* XN     = (unsigned short*)w; w += (size_t)2048 * 1024 * 2;
    float*          UZ     = (float*)w;          w += (size_t)2048 * 4096 * 4;
    float*          UC     = (float*)w;          w += (size_t)2048 * 2048 * 4;
    unsigned short* UCB    = (unsigned short*)w; w += (size_t)2048 * 2048 * 2;
    float*          DBL    = (float*)w;          w += (size_t)2048 * 128 * 4;
    unsigned short* DTR    = (unsigned short*)w; w += (size_t)2048 * 64 * 2;
    float*          DT     = (float*)w;          w += (size_t)2048 * 2048 * 4;
    unsigned short* YG     = (unsigned short*)w; w += (size_t)2048 * 2048 * 2;

    // aliases onto dead buffers:
    // GEMM2 split-K partials -> WIN_T (8MB, dead after GEMM1)
    // scan: aggA -> XN, aggH -> WIN_T[0:4MB), hinit -> WIN_T[4MB:8MB) (partials dead after k_red8)
    float* PART  = (float*)WIN_T;
    float* AGGA  = (float*)XN;
    float* AGGH  = (float*)WIN_T;
    float* HINIT = (float*)((char*)WIN_T + (size_t)4 * 1024 * 1024);

    // weight prep (transpose + bf16)
    k_transpose_cvt<<<dim3(128, 32), 256, 0, stream>>>(W_in,  WIN_T,  1024, 4096, 4096);
    k_transpose_cvt<<<dim3(32, 64),  256, 0, stream>>>(W_out, WOUT_T, 2048, 1024, 1024);
    k_transpose_cvt<<<dim3(64, 2),   256, 0, stream>>>(W_dt,  WDT_T,  64,   2048, 2048);
    k_transpose_cvt<<<dim3(4, 64),   256, 0, stream>>>(W_x,   WX_T,   2048, 96,   128);

    k_ln<<<2048, 256, 0, stream>>>(x, ln_g, ln_b, XN);

    // u,z = xn @ W_in   (2048x4096, K=1024) — 512 blocks
    k_gemm2<128, 128, 0><<<dim3(16, 32, 1), 256, 0, stream>>>(XN, WIN_T, UZ, 1024, 1024, 1024, 4096, 0, nullptr);

    k_conv<<<16384, 256, 0, stream>>>(UZ, conv_w, conv_b, UC, UCB);

    // dbl = uc @ W_x(padded)   (2048x128, K=2048) — split-K x8 -> 256 blocks
    k_gemm2<64, 128, 0><<<dim3(32, 1, 8), 256, 0, stream>>>(UCB, WX_T, PART, 256, 2048, 2048, 128, (size_t)2048 * 128, nullptr);
    k_red8<<<1024, 256, 0, stream>>>(PART, DBL, DTR);

    // dt = softplus(dtr @ W_dt + b_dt)   (2048x2048, K=64) — 256 blocks
    k_gemm2<128, 128, 1><<<dim3(16, 16, 1), 256, 0, stream>>>(DTR, WDT_T, DT, 64, 64, 64, 2048, 0, b_dt);

    // chunked scan (16 chunks of 64, lane-owns-element)
    k_scan_p1<<<256, 256, 0, stream>>>(DT, UC, DBL, A_log, AGGA, AGGH);
    k_scan_p2<<<256, 256, 0, stream>>>(AGGA, AGGH, HINIT);
    k_scan_p3<<<256, 256, 0, stream>>>(DT, UC, DBL, UZ, A_log, D_skip, HINIT, YG);

    // out = yg @ W_out   (2048x1024, K=2048) — 256 blocks
    k_gemm2<64, 128, 0><<<dim3(32, 8, 1), 256, 0, stream>>>(YG, WOUT_T, out, 2048, 2048, 2048, 1024, 0, nullptr);
}

// Round 6
// 283.433 us; speedup vs baseline: 3.5853x; 1.0056x over previous
//
#include <hip/hip_runtime.h>
#include <hip/hip_bf16.h>

// ---------------- types & helpers ----------------
typedef __attribute__((ext_vector_type(4))) float  f32x4;
typedef __attribute__((ext_vector_type(8))) __bf16 bf16x8;

typedef __attribute__((address_space(1))) void gvoid_t;
typedef __attribute__((address_space(3))) void lvoid_t;

__device__ __forceinline__ void gld16(const void* g, void* l) {
    __builtin_amdgcn_global_load_lds((const gvoid_t*)g, (lvoid_t*)l, 16, 0, 0);
}

template <int N> __device__ __forceinline__ void vwait() {
    if constexpr (N == 0)      asm volatile("s_waitcnt vmcnt(0)" ::: "memory");
    else if constexpr (N == 6) asm volatile("s_waitcnt vmcnt(6)" ::: "memory");
    else if constexpr (N == 8) asm volatile("s_waitcnt vmcnt(8)" ::: "memory");
}

__device__ __forceinline__ unsigned short f2bf(float f) {
    unsigned u = __builtin_bit_cast(unsigned, f);
    u += 0x7fffu + ((u >> 16) & 1u);
    return (unsigned short)(u >> 16);
}
__device__ __forceinline__ float bf2f(unsigned short u) {
    return __builtin_bit_cast(float, (unsigned)u << 16);
}
__device__ __forceinline__ float silu(float x) {
    return x / (1.f + __expf(-x));
}

// ---------------- fused prep: LayerNorm + 4 weight transposes ----------------
__device__ __forceinline__ void tr_cvt(const float* __restrict__ in,
                                       unsigned short* __restrict__ out,
                                       int K, int N, int Npad, int bnb, int bkb,
                                       float* sh) {
    float (*t)[33] = (float(*)[33])sh;
    int bn = bnb * 32, bk = bkb * 32;
    int c = threadIdx.x & 31, r0 = threadIdx.x >> 5;
    #pragma unroll
    for (int rr = r0; rr < 32; rr += 8) {
        int k = bk + rr, n = bn + c;
        t[rr][c] = (k < K && n < N) ? in[(size_t)k * N + n] : 0.f;
    }
    __syncthreads();
    #pragma unroll
    for (int rr = r0; rr < 32; rr += 8) {
        int n = bn + rr, k = bk + c;
        if (n < Npad && k < K) out[(size_t)n * K + k] = f2bf(t[c][rr]);
    }
}

__global__ __launch_bounds__(256) void k_prep(const float* __restrict__ x,
                                              const float* __restrict__ g,
                                              const float* __restrict__ b,
                                              unsigned short* __restrict__ xn,
                                              const float* __restrict__ W_in,  unsigned short* __restrict__ WIN_T,
                                              const float* __restrict__ W_out, unsigned short* __restrict__ WOUT_T,
                                              const float* __restrict__ W_dt,  unsigned short* __restrict__ WDT_T,
                                              const float* __restrict__ W_x,   unsigned short* __restrict__ WX_T) {
    __shared__ float sh[32 * 33];
    int bid = blockIdx.x;
    if (bid < 2048) {
        // LayerNorm row
        int row = bid;
        const float4* xr = (const float4*)(x + (size_t)row * 1024);
        float4 v = xr[threadIdx.x];
        float s  = v.x + v.y + v.z + v.w;
        float ss = v.x*v.x + v.y*v.y + v.z*v.z + v.w*v.w;
        #pragma unroll
        for (int o = 32; o > 0; o >>= 1) { s += __shfl_down(s, o); ss += __shfl_down(ss, o); }
        if ((threadIdx.x & 63) == 0) { sh[threadIdx.x >> 6] = s; sh[4 + (threadIdx.x >> 6)] = ss; }
        __syncthreads();
        s  = sh[0] + sh[1] + sh[2] + sh[3];
        ss = sh[4] + sh[5] + sh[6] + sh[7];
        float mu  = s * (1.f / 1024.f);
        float inv = rsqrtf(ss * (1.f / 1024.f) - mu * mu + 1e-5f);
        float4 gv = ((const float4*)g)[threadIdx.x];
        float4 bv = ((const float4*)b)[threadIdx.x];
        ushort4 o4;
        o4.x = f2bf((v.x - mu) * inv * gv.x + bv.x);
        o4.y = f2bf((v.y - mu) * inv * gv.y + bv.y);
        o4.z = f2bf((v.z - mu) * inv * gv.z + bv.z);
        o4.w = f2bf((v.w - mu) * inv * gv.w + bv.w);
        ((ushort4*)xn)[(size_t)row * 256 + threadIdx.x] = o4;
    } else if (bid < 6144) {
        int i = bid - 2048;  tr_cvt(W_in,  WIN_T,  1024, 4096, 4096, i & 127, i >> 7, sh);
    } else if (bid < 8192) {
        int i = bid - 6144;  tr_cvt(W_out, WOUT_T, 2048, 1024, 1024, i & 31,  i >> 5, sh);
    } else if (bid < 8320) {
        int i = bid - 8192;  tr_cvt(W_dt,  WDT_T,  64,   2048, 2048, i & 63,  i >> 6, sh);
    } else {
        int i = bid - 8320;  tr_cvt(W_x,   WX_T,   2048, 96,   128,  i & 3,   i >> 2, sh);
    }
}

// ---------------- pipelined bf16 MFMA GEMM (2-phase, BK=64, XOR-swizzled LDS) ----
// EPI: 0 = fp32 store to C; 1 = softplus(x+bias[col]) -> C;
//      2 = col<2048 ? fp32->C(ld 2048) : bf16(silu)->C2(ld 2048)
template <int BM, int BN, int EPI>
__global__ __launch_bounds__(256) void k_gemm2(const unsigned short* __restrict__ A,
                                               const unsigned short* __restrict__ Bt,
                                               float* __restrict__ C,
                                               unsigned short* __restrict__ C2,
                                               int kchunk, int lda, int ldb, int ldc,
                                               size_t zstride,
                                               const float* __restrict__ bias) {
    constexpr int PA = BM / 32, PB = BN / 32, NV = PA + PB;
    constexpr int MF = BM / 32, NF = BN / 32;
    __shared__ __attribute__((aligned(16))) unsigned short smA[2 * BM * 64];
    __shared__ __attribute__((aligned(16))) unsigned short smB[2 * BN * 64];

    int tid = threadIdx.x, wave = tid >> 6, lane = tid & 63;
    int bm = blockIdx.x * BM, bn = blockIdx.y * BN;
    int kstart = blockIdx.z * kchunk;
    int nt = kchunk >> 6;
    C += (size_t)blockIdx.z * zstride;
    int wm = (wave >> 1) * (BM / 2), wn = (wave & 1) * (BN / 2);
    int lr = lane & 15, lq = lane >> 4;
    int srow = wave * 8 + (lane >> 3);
    int scg  = lane & 7;

    f32x4 acc[MF][NF] = {};

    auto STAGE = [&](int buf, int k0) {
        unsigned short* dA = smA + buf * (BM * 64) + wave * 512;
        unsigned short* dB = smB + buf * (BN * 64) + wave * 512;
        #pragma unroll
        for (int p = 0; p < PA; ++p) {
            int row = p * 32 + srow;
            int gcol = ((scg ^ (row & 7)) << 3) + k0;
            gld16(A + (size_t)(bm + row) * lda + gcol, dA + p * 2048);
        }
        #pragma unroll
        for (int p = 0; p < PB; ++p) {
            int row = p * 32 + srow;
            int gcol = ((scg ^ (row & 7)) << 3) + k0;
            gld16(Bt + (size_t)(bn + row) * ldb + gcol, dB + p * 2048);
        }
    };

    STAGE(0, kstart);
    for (int t = 0; t < nt; ++t) {
        int cur = t & 1;
        if (t + 1 < nt) { STAGE(cur ^ 1, kstart + (t + 1) * 64); vwait<NV>(); }
        else            { vwait<0>(); }
        __builtin_amdgcn_s_barrier();
        const unsigned short* sA = smA + cur * (BM * 64);
        const unsigned short* sB = smB + cur * (BN * 64);
        #pragma unroll
        for (int ks = 0; ks < 2; ++ks) {
            int cg = (ks * 4 + lq) ^ (lr & 7);
            bf16x8 af[MF], bfv[NF];
            #pragma unroll
            for (int i = 0; i < MF; ++i)
                af[i] = *(const bf16x8*)(sA + (wm + i * 16 + lr) * 64 + (cg << 3));
            #pragma unroll
            for (int i = 0; i < NF; ++i)
                bfv[i] = *(const bf16x8*)(sB + (wn + i * 16 + lr) * 64 + (cg << 3));
            #pragma unroll
            for (int mi = 0; mi < MF; ++mi)
                #pragma unroll
                for (int ni = 0; ni < NF; ++ni)
                    acc[mi][ni] = __builtin_amdgcn_mfma_f32_16x16x32_bf16(af[mi], bfv[ni], acc[mi][ni], 0, 0, 0);
        }
        __builtin_amdgcn_s_barrier();
    }

    #pragma unroll
    for (int mi = 0; mi < MF; ++mi) {
        #pragma unroll
        for (int ni = 0; ni < NF; ++ni) {
            int c = bn + wn + ni * 16 + lr;
            #pragma unroll
            for (int v = 0; v < 4; ++v) {
                int r = bm + wm + mi * 16 + (lq << 2) + v;
                float val = acc[mi][ni][v];
                if (EPI == 0) {
                    C[(size_t)r * ldc + c] = val;
                } else if (EPI == 1) {
                    val += bias[c];
                    val = (val > 20.f) ? val : log1pf(__expf(val));
                    C[(size_t)r * ldc + c] = val;
                } else {
                    if (c < 2048) C[(size_t)r * 2048 + c] = val;
                    else          C2[(size_t)r * 2048 + (c - 2048)] = f2bf(silu(val));
                }
            }
        }
    }
}

// ---------------- split-K reduce (8 partials) + dtr bf16 ----------------
__global__ __launch_bounds__(256) void k_red8(const float* __restrict__ part,
                                              float* __restrict__ dbl,
                                              unsigned short* __restrict__ dtr) {
    int idx = blockIdx.x * 256 + threadIdx.x;   // 2048*128
    float s = 0.f;
    #pragma unroll
    for (int z = 0; z < 8; ++z) s += part[(size_t)z * 262144 + idx];
    dbl[idx] = s;
    int r = idx >> 7, c = idx & 127;
    if (c < 64) dtr[r * 64 + c] = f2bf(s);
}

// ---------------- causal depthwise conv (width 4) + SiLU -> bf16 only ----------
__global__ __launch_bounds__(256) void k_conv2(const float* __restrict__ U,
                                               const float* __restrict__ cw,
                                               const float* __restrict__ cb,
                                               unsigned short* __restrict__ ucb) {
    int idx = blockIdx.x * 256 + threadIdx.x;   // (b*L+l)*2048 + e
    int e  = idx & 2047;
    int bl = idx >> 11;
    int l  = bl & 1023;
    float acc = cb[e];
    float4 wv = *(const float4*)(cw + e * 4);
    float w4[4] = {wv.x, wv.y, wv.z, wv.w};
    #pragma unroll
    for (int k = 0; k < 4; ++k) {
        int ls = l - 3 + k;
        if (ls >= 0) acc += w4[k] * U[(size_t)(bl - 3 + k) * 2048 + e];
    }
    ucb[idx] = f2bf(silu(acc));
}

// ---------------- chunked scan, lane-owns-element, on-the-fly conv ------------
// 16 chunks of 64. Thread owns e, all 16 states in regs.
// U/DT/SZ/YG: [b*1024+l][2048]. DBL: [b*1024+l][128], B@64, C@80.
// AGGH: ((b*16+c)*16+n)*2048+e ; SDT: (b*16+c)*2048+e

__global__ __launch_bounds__(256) void k_scan_p1(const float* __restrict__ U,
                                                 const float* __restrict__ dt,
                                                 const float* __restrict__ dbl,
                                                 const float* __restrict__ A_log,
                                                 const float* __restrict__ cw,
                                                 const float* __restrict__ cb,
                                                 float* __restrict__ aggH,
                                                 float* __restrict__ sdtb) {
    __shared__ float sB[64][16];
    int bid = blockIdx.x;
    int c = bid & 15, eblk = (bid >> 4) & 7, b = bid >> 7;
    int t = threadIdx.x;
    int e = eblk * 256 + t;
    int bl0 = b * 1024 + c * 64;
    {
        int r = t >> 2, j4 = t & 3;
        *(float4*)&sB[r][j4 * 4] = *(const float4*)(dbl + (size_t)(bl0 + r) * 128 + 64 + j4 * 4);
    }
    __syncthreads();
    float Aen[16];
    #pragma unroll
    for (int n = 0; n < 16; ++n) Aen[n] = -__expf(A_log[e * 16 + n]);
    bool fastA = true;
    #pragma unroll
    for (int n = 1; n < 16; ++n)
        fastA = fastA && (fabsf(Aen[n] - (n + 1) * Aen[0]) <= 1e-3f);
    float4 wv = *(const float4*)(cw + e * 4);
    float cbv = cb[e];
    float um3 = 0.f, um2 = 0.f, um1 = 0.f;
    if (c > 0) {
        um3 = U[(size_t)(bl0 - 3) * 2048 + e];
        um2 = U[(size_t)(bl0 - 2) * 2048 + e];
        um1 = U[(size_t)(bl0 - 1) * 2048 + e];
    }
    float h[16];
    #pragma unroll
    for (int n = 0; n < 16; ++n) h[n] = 0.f;
    float sdt = 0.f;
    size_t iu = (size_t)bl0 * 2048 + e;
    #pragma unroll 4
    for (int l = 0; l < 64; ++l) {
        float u0  = U[iu];
        float dtv = dt[iu];
        float ucv = silu(cbv + wv.x * um3 + wv.y * um2 + wv.z * um1 + wv.w * u0);
        um3 = um2; um2 = um1; um1 = u0;
        float dtu = dtv * ucv;
        float dA[16];
        if (fastA) {
            float p = __expf(dtv * Aen[0]);
            float cur = p;
            #pragma unroll
            for (int n = 0; n < 16; ++n) { dA[n] = cur; cur *= p; }
        } else {
            #pragma unroll
            for (int n = 0; n < 16; ++n) dA[n] = __expf(dtv * Aen[n]);
        }
        #pragma unroll
        for (int n = 0; n < 16; ++n)
            h[n] = fmaf(dA[n], h[n], dtu * sB[l][n]);
        sdt += dtv;
        iu += 2048;
    }
    size_t o = ((size_t)(b * 16 + c) * 16) * 2048 + e;
    #pragma unroll
    for (int n = 0; n < 16; ++n) aggH[o + (size_t)n * 2048] = h[n];
    sdtb[(size_t)(b * 16 + c) * 2048 + e] = sdt;
}

__global__ __launch_bounds__(256) void k_scan_p3(const float* __restrict__ U,
                                                 const float* __restrict__ dt,
                                                 const float* __restrict__ dbl,
                                                 const unsigned short* __restrict__ sz,
                                                 const float* __restrict__ A_log,
                                                 const float* __restrict__ D_skip,
                                                 const float* __restrict__ cw,
                                                 const float* __restrict__ cb,
                                                 const float* __restrict__ aggH,
                                                 const float* __restrict__ sdtb,
                                                 unsigned short* __restrict__ yg) {
    __shared__ float sBC[64][32];
    int bid = blockIdx.x;
    int c = bid & 15, eblk = (bid >> 4) & 7, b = bid >> 7;
    int t = threadIdx.x;
    int e = eblk * 256 + t;
    int bl0 = b * 1024 + c * 64;
    #pragma unroll
    for (int i = t; i < 512; i += 256) {
        int r = i >> 3, j = i & 7;
        *(float4*)&sBC[r][j * 4] = *(const float4*)(dbl + (size_t)(bl0 + r) * 128 + 64 + j * 4);
    }
    __syncthreads();
    float Aen[16];
    #pragma unroll
    for (int n = 0; n < 16; ++n) Aen[n] = -__expf(A_log[e * 16 + n]);
    bool fastA = true;
    #pragma unroll
    for (int n = 1; n < 16; ++n)
        fastA = fastA && (fabsf(Aen[n] - (n + 1) * Aen[0]) <= 1e-3f);
    float De = D_skip[e];
    float4 wv = *(const float4*)(cw + e * 4);
    float cbv = cb[e];
    // chunk-prefix (absorbed pass 2): h = scan of chunk aggregates 0..c-1
    float h[16];
    #pragma unroll
    for (int n = 0; n < 16; ++n) h[n] = 0.f;
    for (int cc = 0; cc < c; ++cc) {
        float sdtc = sdtb[(size_t)(b * 16 + cc) * 2048 + e];
        size_t oa = ((size_t)(b * 16 + cc) * 16) * 2048 + e;
        float aa[16];
        if (fastA) {
            float p = __expf(sdtc * Aen[0]);
            float cur = p;
            #pragma unroll
            for (int n = 0; n < 16; ++n) { aa[n] = cur; cur *= p; }
        } else {
            #pragma unroll
            for (int n = 0; n < 16; ++n) aa[n] = __expf(sdtc * Aen[n]);
        }
        #pragma unroll
        for (int n = 0; n < 16; ++n)
            h[n] = fmaf(aa[n], h[n], aggH[oa + (size_t)n * 2048]);
    }
    float um3 = 0.f, um2 = 0.f, um1 = 0.f;
    if (c > 0) {
        um3 = U[(size_t)(bl0 - 3) * 2048 + e];
        um2 = U[(size_t)(bl0 - 2) * 2048 + e];
        um1 = U[(size_t)(bl0 - 1) * 2048 + e];
    }
    size_t iu = (size_t)bl0 * 2048 + e;
    #pragma unroll 4
    for (int l = 0; l < 64; ++l) {
        float u0  = U[iu];
        float dtv = dt[iu];
        float szv = bf2f(sz[iu]);
        float ucv = silu(cbv + wv.x * um3 + wv.y * um2 + wv.z * um1 + wv.w * u0);
        um3 = um2; um2 = um1; um1 = u0;
        float dtu = dtv * ucv;
        float dA[16];
        if (fastA) {
            float p = __expf(dtv * Aen[0]);
            float cur = p;
            #pragma unroll
            for (int n = 0; n < 16; ++n) { dA[n] = cur; cur *= p; }
        } else {
            #pragma unroll
            for (int n = 0; n < 16; ++n) dA[n] = __expf(dtv * Aen[n]);
        }
        float y = 0.f;
        #pragma unroll
        for (int n = 0; n < 16; ++n) {
            h[n] = fmaf(dA[n], h[n], dtu * sBC[l][n]);
            y = fmaf(h[n], sBC[l][16 + n], y);
        }
        y = (y + ucv * De) * szv;
        yg[iu] = f2bf(y);
        iu += 2048;
    }
}

// ---------------- launch ----------------
extern "C" void kernel_launch(void* const* d_in, const int* in_sizes, int n_in,
                              void* d_out, int out_size, void* d_ws, size_t ws_size,
                              hipStream_t stream) {
    const float* x      = (const float*)d_in[0];
    const float* ln_g   = (const float*)d_in[1];
    const float* ln_b   = (const float*)d_in[2];
    const float* W_in   = (const float*)d_in[3];
    const float* conv_w = (const float*)d_in[4];
    const float* conv_b = (const float*)d_in[5];
    const float* W_x    = (const float*)d_in[6];
    const float* W_dt   = (const float*)d_in[7];
    const float* b_dt   = (const float*)d_in[8];
    const float* A_log  = (const float*)d_in[9];
    const float* D_skip = (const float*)d_in[10];
    const float* W_out  = (const float*)d_in[11];
    float* out = (float*)d_out;

    const size_t needed =
        (size_t)4096 * 1024 * 2 + (size_t)1024 * 2048 * 2 + (size_t)2048 * 64 * 2 +
        (size_t)128 * 2048 * 2 + (size_t)2048 * 1024 * 2 + (size_t)2048 * 4096 * 4 +
        (size_t)2048 * 2048 * 4 + (size_t)2048 * 2048 * 2 + (size_t)2048 * 128 * 4 +
        (size_t)2048 * 64 * 2 + (size_t)2048 * 2048 * 4 + (size_t)2048 * 2048 * 2;
    if (ws_size < needed) return;

    char* w = (char*)d_ws;
    unsigned short* WIN_T  = (unsigned short*)w; w += (size_t)4096 * 1024 * 2;   // 8 MB
    unsigned short* WOUT_T = (unsigned short*)w; w += (size_t)1024 * 2048 * 2;   // 4 MB
    unsigned short* WDT_T  = (unsigned short*)w; w += (size_t)2048 * 64 * 2;
    unsigned short* WX_T   = (unsigned short*)w; w += (size_t)128 * 2048 * 2;
    unsigned short* XN     = (unsigned short*)w; w += (size_t)2048 * 1024 * 2;   // 4 MB
    float*          U      = (float*)w;          w += (size_t)2048 * 2048 * 4;   // 16 MB
    unsigned short* SZ     = (unsigned short*)w; w += (size_t)2048 * 2048 * 2;   // 8 MB
    w += (size_t)2048 * 2048 * 2;                                                // spare
    unsigned short* UCB    = (unsigned short*)w; w += (size_t)2048 * 2048 * 2;   // 8 MB
    w += (size_t)2048 * 2048 * 2 + (size_t)2048 * 2048 * 2;                      // spare
    float*          DBL    = (float*)w;          w += (size_t)2048 * 128 * 4;
    unsigned short* DTR    = (unsigned short*)w; w += (size_t)2048 * 64 * 2;
    float*          DT     = (float*)w;          w += (size_t)2048 * 2048 * 4;   // 16 MB
    unsigned short* YG     = (unsigned short*)w; w += (size_t)2048 * 2048 * 2;   // 8 MB

    // aliases on dead regions: PART (8MB) and SDT on WIN_T (dead after GEMM1 / red8);
    // AGGH (4MB) on XN (dead after GEMM1)
    float* PART = (float*)WIN_T;
    float* SDT  = (float*)WIN_T;
    float* AGGH = (float*)XN;

    // 1. prep: LN + all weight transposes
    k_prep<<<8576, 256, 0, stream>>>(x, ln_g, ln_b, XN,
                                     W_in, WIN_T, W_out, WOUT_T, W_dt, WDT_T, W_x, WX_T);

    // 2. u,z = xn @ W_in ; u -> U fp32, z -> SZ = silu(z) bf16
    k_gemm2<128, 128, 2><<<dim3(16, 32, 1), 256, 0, stream>>>(XN, WIN_T, U, SZ, 1024, 1024, 1024, 2048, 0, nullptr);

    // 3. uc(bf16) = silu(conv(u))
    k_conv2<<<16384, 256, 0, stream>>>(U, conv_w, conv_b, UCB);

    // 4. dbl partials = uc @ W_x (split-K x8)
    k_gemm2<64, 128, 0><<<dim3(32, 1, 8), 256, 0, stream>>>(UCB, WX_T, PART, nullptr, 256, 2048, 2048, 128, (size_t)2048 * 128, nullptr);

    // 5. reduce partials -> DBL fp32 + DTR bf16
    k_red8<<<1024, 256, 0, stream>>>(PART, DBL, DTR);

    // 6. dt = softplus(dtr @ W_dt + b_dt)
    k_gemm2<128, 128, 1><<<dim3(16, 16, 1), 256, 0, stream>>>(DTR, WDT_T, DT, nullptr, 64, 64, 64, 2048, 0, b_dt);

    // 7/8. chunked scan (conv on the fly; p3 absorbs inter-chunk prefix)
    k_scan_p1<<<256, 256, 0, stream>>>(U, DT, DBL, A_log, conv_w, conv_b, AGGH, SDT);
    k_scan_p3<<<256, 256, 0, stream>>>(U, DT, DBL, SZ, A_log, D_skip, conv_w, conv_b, AGGH, SDT, YG);

    // 9. out = yg @ W_out
    k_gemm2<64, 128, 0><<<dim3(32, 8, 1), 256, 0, stream>>>(YG, WOUT_T, out, nullptr, 2048, 2048, 2048, 1024, 0, nullptr);
}